// Round 1
// baseline (1891.958 us; speedup 1.0000x reference)
//
#include <hip/hip_runtime.h>

// MultiHeadedAttention: B=8, S=1024, D=1024, H=16, dk=64, fp32.
// out = Dense( Attn_policy( Q=q@WqT+bq, K=k@WkT+bk, V=v@WvT+bv, policy ) )
// p_attn = (exp(QK^T/8)*pol + EPS/S) / (sum + EPS)
// x = (sum_k sc*v + (EPS/S)*sum_k v) / (den + EPS)   <- algebraic fusion

#define Sdim 1024
#define Ddim 1024
#define Hn   16
#define Bn   8

// ---------------------------------------------------------------------------
// GEMM: C[M][1024] = A[M][1024] @ W[1024][1024]^T + bias   (torch Linear)
// 64x64 tile, BK=16, 256 threads, 4x4 micro-tile.
// ---------------------------------------------------------------------------
__global__ __launch_bounds__(256) void gemm_bt(const float* __restrict__ A,
                                               const float* __restrict__ Wt,
                                               const float* __restrict__ bias,
                                               float* __restrict__ C) {
    __shared__ float As[16][68];
    __shared__ float Ws[16][68];
    const int tid = threadIdx.x;
    const int tx = tid & 15;   // n micro
    const int ty = tid >> 4;   // m micro
    const int m0 = blockIdx.x * 64;
    const int n0 = blockIdx.y * 64;
    const int lrow = tid >> 2;        // 0..63
    const int lcg  = (tid & 3) * 4;   // 0,4,8,12

    float acc[4][4] = {};
    const float* Aptr = A  + (size_t)(m0 + lrow) * Ddim + lcg;
    const float* Wptr = Wt + (size_t)(n0 + lrow) * Ddim + lcg;

    for (int k0 = 0; k0 < Ddim; k0 += 16) {
        const float4 a4 = *(const float4*)(Aptr + k0);
        const float4 w4 = *(const float4*)(Wptr + k0);
        __syncthreads();
        As[lcg + 0][lrow] = a4.x;
        As[lcg + 1][lrow] = a4.y;
        As[lcg + 2][lrow] = a4.z;
        As[lcg + 3][lrow] = a4.w;
        Ws[lcg + 0][lrow] = w4.x;
        Ws[lcg + 1][lrow] = w4.y;
        Ws[lcg + 2][lrow] = w4.z;
        Ws[lcg + 3][lrow] = w4.w;
        __syncthreads();
#pragma unroll
        for (int k = 0; k < 16; ++k) {
            const float4 av = *(const float4*)&As[k][ty * 4];
            const float4 wv = *(const float4*)&Ws[k][tx * 4];
            const float am[4] = {av.x, av.y, av.z, av.w};
            const float wm[4] = {wv.x, wv.y, wv.z, wv.w};
#pragma unroll
            for (int i = 0; i < 4; ++i)
#pragma unroll
                for (int j = 0; j < 4; ++j)
                    acc[i][j] = fmaf(am[i], wm[j], acc[i][j]);
        }
    }
    const float4 bv = *(const float4*)(bias + n0 + tx * 4);
    const float bm[4] = {bv.x, bv.y, bv.z, bv.w};
#pragma unroll
    for (int i = 0; i < 4; ++i) {
        float4 o;
        o.x = acc[i][0] + bm[0];
        o.y = acc[i][1] + bm[1];
        o.z = acc[i][2] + bm[2];
        o.w = acc[i][3] + bm[3];
        *(float4*)(C + (size_t)(m0 + ty * 4 + i) * Ddim + n0 + tx * 4) = o;
    }
}

// ---------------------------------------------------------------------------
// Policy attention, flash-style: one block per (b, h, 64-row q-tile).
// Q/K/V projected tensors are in merged layout [B*S][D], head h = cols h*64..
// P-tile overwrites the K-tile in LDS to stay under 64 KB static LDS.
// ---------------------------------------------------------------------------
__global__ __launch_bounds__(256) void attn_kernel(const float* __restrict__ Qp,
                                                   const float* __restrict__ Kp,
                                                   const float* __restrict__ Vp,
                                                   const float* __restrict__ pol,
                                                   float* __restrict__ Xb) {
    __shared__ float Qs[64][68];
    __shared__ float KPs[64][68];   // K tile, then overwritten with P tile
    __shared__ float Vs[64][68];
    __shared__ float dred[64][17];
    __shared__ float pols[64];

    const int tid = threadIdx.x;
    const int tx = tid & 15;
    const int ty = tid >> 4;
    const int b = blockIdx.x >> 4;
    const int h = blockIdx.x & 15;
    const int q0 = blockIdx.y * 64;
    const size_t baseBS = (size_t)b * Sdim;
    const int col0 = h * 64;

    // load Q tile [64 rows][64 dk]
    {
        const int lr = tid >> 4;
        const int lc = (tid & 15) * 4;
#pragma unroll
        for (int r = 0; r < 4; ++r) {
            const int row = lr + r * 16;
            *(float4*)&Qs[row][lc] =
                *(const float4*)(Qp + (baseBS + q0 + row) * Ddim + col0 + lc);
        }
    }

    float xacc[4][4] = {};
    float den_acc[4] = {0.f, 0.f, 0.f, 0.f};
    float sumV[4] = {0.f, 0.f, 0.f, 0.f};

    for (int kt = 0; kt < 16; ++kt) {
        const int kbase = kt * 64;
        __syncthreads();  // prev iteration done reading KPs/Vs (also covers Q load)
        {
            const int lr = tid >> 4;
            const int lc = (tid & 15) * 4;
#pragma unroll
            for (int r = 0; r < 4; ++r) {
                const int row = lr + r * 16;
                *(float4*)&KPs[row][lc] =
                    *(const float4*)(Kp + (baseBS + kbase + row) * Ddim + col0 + lc);
                *(float4*)&Vs[row][lc] =
                    *(const float4*)(Vp + (baseBS + kbase + row) * Ddim + col0 + lc);
            }
        }
        if (tid < 64) pols[tid] = pol[baseBS + kbase + tid];
        __syncthreads();

        // scores = Q . K^T  (per-thread 4x4)
        float sc[4][4] = {};
#pragma unroll
        for (int d4 = 0; d4 < 64; d4 += 4) {
            float4 qv[4], kv[4];
#pragma unroll
            for (int i = 0; i < 4; ++i) qv[i] = *(const float4*)&Qs[ty * 4 + i][d4];
#pragma unroll
            for (int j = 0; j < 4; ++j) kv[j] = *(const float4*)&KPs[tx * 4 + j][d4];
#pragma unroll
            for (int i = 0; i < 4; ++i)
#pragma unroll
                for (int j = 0; j < 4; ++j) {
                    sc[i][j] = fmaf(qv[i].x, kv[j].x, sc[i][j]);
                    sc[i][j] = fmaf(qv[i].y, kv[j].y, sc[i][j]);
                    sc[i][j] = fmaf(qv[i].z, kv[j].z, sc[i][j]);
                    sc[i][j] = fmaf(qv[i].w, kv[j].w, sc[i][j]);
                }
        }
        float pl[4];
#pragma unroll
        for (int j = 0; j < 4; ++j) pl[j] = pols[tx * 4 + j];
#pragma unroll
        for (int i = 0; i < 4; ++i)
#pragma unroll
            for (int j = 0; j < 4; ++j) {
                const float v = __expf(sc[i][j] * 0.125f) * pl[j];
                sc[i][j] = v;
                den_acc[i] += v;
            }
        __syncthreads();  // everyone done reading K tile
#pragma unroll
        for (int i = 0; i < 4; ++i)
            *(float4*)&KPs[ty * 4 + i][tx * 4] =
                make_float4(sc[i][0], sc[i][1], sc[i][2], sc[i][3]);
        __syncthreads();

        // x += P . V ; also accumulate column sums of V
#pragma unroll
        for (int kk = 0; kk < 64; kk += 4) {
            float4 p4[4];
#pragma unroll
            for (int i = 0; i < 4; ++i) p4[i] = *(const float4*)&KPs[ty * 4 + i][kk];
            float pm[4][4];
#pragma unroll
            for (int i = 0; i < 4; ++i) {
                pm[i][0] = p4[i].x; pm[i][1] = p4[i].y;
                pm[i][2] = p4[i].z; pm[i][3] = p4[i].w;
            }
#pragma unroll
            for (int u = 0; u < 4; ++u) {
                const float4 vv = *(const float4*)&Vs[kk + u][tx * 4];
                const float vm[4] = {vv.x, vv.y, vv.z, vv.w};
#pragma unroll
                for (int j = 0; j < 4; ++j) sumV[j] += vm[j];
#pragma unroll
                for (int i = 0; i < 4; ++i)
#pragma unroll
                    for (int j = 0; j < 4; ++j)
                        xacc[i][j] = fmaf(pm[i][u], vm[j], xacc[i][j]);
            }
        }
    }

    // reduce den across the 16 tx columns
#pragma unroll
    for (int i = 0; i < 4; ++i) dred[ty * 4 + i][tx] = den_acc[i];
    __syncthreads();
    constexpr float EPS  = 1e-6f;
    constexpr float EPSS = 1e-6f / 1024.0f;
#pragma unroll
    for (int i = 0; i < 4; ++i) {
        float den = EPS;
#pragma unroll
        for (int t = 0; t < 16; ++t) den += dred[ty * 4 + i][t];
        const float r = 1.0f / den;
        float4 o;
        o.x = (xacc[i][0] + EPSS * sumV[0]) * r;
        o.y = (xacc[i][1] + EPSS * sumV[1]) * r;
        o.z = (xacc[i][2] + EPSS * sumV[2]) * r;
        o.w = (xacc[i][3] + EPSS * sumV[3]) * r;
        *(float4*)(Xb + (baseBS + q0 + ty * 4 + i) * Ddim + col0 + tx * 4) = o;
    }
}

// ---------------------------------------------------------------------------
extern "C" void kernel_launch(void* const* d_in, const int* in_sizes, int n_in,
                              void* d_out, int out_size, void* d_ws, size_t ws_size,
                              hipStream_t stream) {
    const float* query   = (const float*)d_in[0];
    const float* key     = (const float*)d_in[1];
    const float* value   = (const float*)d_in[2];
    const float* policy  = (const float*)d_in[3];
    const float* wq_w    = (const float*)d_in[4];
    const float* wq_b    = (const float*)d_in[5];
    const float* wk_w    = (const float*)d_in[6];
    const float* wk_b    = (const float*)d_in[7];
    const float* wv_w    = (const float*)d_in[8];
    const float* wv_b    = (const float*)d_in[9];
    const float* dense_w = (const float*)d_in[10];
    const float* dense_b = (const float*)d_in[11];
    float* out = (float*)d_out;

    const size_t SZ = (size_t)Bn * Sdim * Ddim;  // 8M floats = 32 MB
    float* qp = (float*)d_ws;
    float* kp = qp + SZ;
    float* vp = kp + SZ;
    float* xb = vp + SZ;

    const dim3 gg(Bn * Sdim / 64, Ddim / 64);  // (128, 16)
    gemm_bt<<<gg, 256, 0, stream>>>(query, wq_w, wq_b, qp);
    gemm_bt<<<gg, 256, 0, stream>>>(key,   wk_w, wk_b, kp);
    gemm_bt<<<gg, 256, 0, stream>>>(value, wv_w, wv_b, vp);

    const dim3 ga(Bn * Hn, Sdim / 64);  // (128, 16)
    attn_kernel<<<ga, 256, 0, stream>>>(qp, kp, vp, policy, xb);

    gemm_bt<<<gg, 256, 0, stream>>>(xb, dense_w, dense_b, out);
}

// Round 2
// 414.090 us; speedup vs baseline: 4.5690x; 4.5690x over previous
//
#include <hip/hip_runtime.h>

// MultiHeadedAttention: B=8, S=1024, D=1024, H=16, dk=64.
// bf16 MFMA pipeline:
//   cvt(q,k,v,weights) -> gemm_bt_mfma(QKV proj, bf16 out) -> attn_mfma -> gemm_bt_mfma(dense, fp32 out)
// attention: p = exp(QK^T/8)*pol; x = (sum p*v + EPS/S * sum v) / (sum p + EPS)

#define Sdim 1024
#define Ddim 1024

typedef unsigned short u16;
typedef float f32x4 __attribute__((ext_vector_type(4)));
typedef __bf16 bf16x8 __attribute__((ext_vector_type(8)));
typedef u16 u16x8 __attribute__((ext_vector_type(8)));

typedef __attribute__((address_space(3))) void lds_void;
typedef __attribute__((address_space(1))) void gbl_void;

__device__ __forceinline__ u16 f2bf(float f) {
    unsigned u = __float_as_uint(f);
    u += 0x7fffu + ((u >> 16) & 1u);   // RNE
    return (u16)(u >> 16);
}
__device__ __forceinline__ float bf2f(u16 h) {
    return __uint_as_float(((unsigned)h) << 16);
}
__device__ __forceinline__ void gld16(const void* g, void* l) {
    __builtin_amdgcn_global_load_lds((const gbl_void*)g, (lds_void*)l, 16, 0, 0);
}

// ---------------------------------------------------------------------------
// fp32 -> bf16 elementwise convert (8 elems/thread)
// ---------------------------------------------------------------------------
__global__ __launch_bounds__(256) void cvt_bf16(const float* __restrict__ s,
                                                u16* __restrict__ d, int n) {
    const int i = (blockIdx.x * 256 + threadIdx.x) * 8;
    if (i >= n) return;
    const float4 a = *(const float4*)(s + i);
    const float4 b = *(const float4*)(s + i + 4);
    u16x8 o;
    o[0] = f2bf(a.x); o[1] = f2bf(a.y); o[2] = f2bf(a.z); o[3] = f2bf(a.w);
    o[4] = f2bf(b.x); o[5] = f2bf(b.y); o[6] = f2bf(b.z); o[7] = f2bf(b.w);
    *(u16x8*)(d + i) = o;
}

// ---------------------------------------------------------------------------
// C[M][1024] = A[M][1024] @ W[1024][1024]^T + bias    (bf16 in, bf16/fp32 out)
// 128x128 tile, BK=32, 256 threads (4 waves as 2x2 of 64x64), m97 structure:
// global_load_lds width=16 staging, ds_read_b128 frags, 16 MFMA/wave/k-iter.
// ---------------------------------------------------------------------------
template <bool OUT_BF16>
__global__ __launch_bounds__(256) void gemm_bt_mfma(const u16* __restrict__ A,
                                                    const u16* __restrict__ W,
                                                    const float* __restrict__ bias,
                                                    void* __restrict__ Cout) {
    __shared__ u16 As[128 * 32];
    __shared__ u16 Bs[128 * 32];
    const int tid  = threadIdx.x;
    const int wave = tid >> 6;
    const int lane = tid & 63;
    const int l15  = lane & 15;
    const int quad = lane >> 4;
    const int m0 = blockIdx.x * 128;
    const int n0 = blockIdx.y * 128;
    const int wm = (wave >> 1) * 64;
    const int wn = (wave & 1) * 64;

    // staging coords: inst e covers tile elements [e*2048 + wave*512 + lane*8, +8)
    const int e0 = wave * 512 + lane * 8;
    const int r0 = e0 >> 5, c0 = e0 & 31;
    const int e1 = 2048 + e0;
    const int r1 = e1 >> 5, c1 = e1 & 31;
    const u16* Ag0 = A + (size_t)(m0 + r0) * Ddim + c0;
    const u16* Ag1 = A + (size_t)(m0 + r1) * Ddim + c1;
    const u16* Wg0 = W + (size_t)(n0 + r0) * Ddim + c0;
    const u16* Wg1 = W + (size_t)(n0 + r1) * Ddim + c1;
    u16* As0 = As + wave * 512;          // wave-uniform LDS dests
    u16* As1 = As + 2048 + wave * 512;
    u16* Bs0 = Bs + wave * 512;
    u16* Bs1 = Bs + 2048 + wave * 512;

    f32x4 acc[4][4] = {};

    for (int k0 = 0; k0 < Ddim; k0 += 32) {
        __syncthreads();
        gld16(Ag0 + k0, As0);
        gld16(Ag1 + k0, As1);
        gld16(Wg0 + k0, Bs0);
        gld16(Wg1 + k0, Bs1);
        __syncthreads();
        bf16x8 af[4], bfr[4];
#pragma unroll
        for (int i = 0; i < 4; ++i)
            af[i] = *(const bf16x8*)(As + (wm + i * 16 + l15) * 32 + quad * 8);
#pragma unroll
        for (int j = 0; j < 4; ++j)
            bfr[j] = *(const bf16x8*)(Bs + (wn + j * 16 + l15) * 32 + quad * 8);
#pragma unroll
        for (int i = 0; i < 4; ++i)
#pragma unroll
            for (int j = 0; j < 4; ++j)
                acc[i][j] = __builtin_amdgcn_mfma_f32_16x16x32_bf16(af[i], bfr[j],
                                                                    acc[i][j], 0, 0, 0);
    }

    float bv[4];
#pragma unroll
    for (int j = 0; j < 4; ++j) bv[j] = bias[n0 + wn + j * 16 + l15];
#pragma unroll
    for (int i = 0; i < 4; ++i)
#pragma unroll
        for (int j = 0; j < 4; ++j)
#pragma unroll
            for (int r = 0; r < 4; ++r) {
                const int row = m0 + wm + i * 16 + quad * 4 + r;
                const int col = n0 + wn + j * 16 + l15;
                const float v = acc[i][j][r] + bv[j];
                if (OUT_BF16)
                    ((u16*)Cout)[(size_t)row * Ddim + col] = f2bf(v);
                else
                    ((float*)Cout)[(size_t)row * Ddim + col] = v;
            }
}

// ---------------------------------------------------------------------------
// MFMA flash attention with policy normalization.
// Block = (b,h, 64 q-rows); 4 waves, each owning 16 q-rows.
// k-tiles of 128. All LDS tiles padded so row stride = 4 dwords (mod 32).
// ---------------------------------------------------------------------------
__global__ __launch_bounds__(256) void attn_mfma(const u16* __restrict__ Qp,
                                                 const u16* __restrict__ Kp,
                                                 const u16* __restrict__ Vp,
                                                 const float* __restrict__ pol,
                                                 u16* __restrict__ Xb) {
    __shared__ u16 Qs[64][72];        //  9216 B  Q[m][dk]
    __shared__ u16 Ks[128][72];       // 18432 B  K[kpos][dk]
    __shared__ u16 Vt[64][136];       // 17408 B  V^T[dk][kpos]
    __shared__ u16 Pw[4][16][136];    // 17408 B  per-wave P[m][kpos]
    __shared__ float pols[128];
    __shared__ float sumv_part[4][64];
    __shared__ float sumv_s[64];

    const int tid  = threadIdx.x;
    const int w    = tid >> 6;
    const int lane = tid & 63;
    const int l15  = lane & 15;
    const int quad = lane >> 4;
    const int b = blockIdx.x >> 4;
    const int h = blockIdx.x & 15;
    const int q0 = blockIdx.y * 64;
    const size_t bS = (size_t)b * Sdim;
    const int col0 = h * 64;

    // stage Q tile (64x64)
#pragma unroll
    for (int p = 0; p < 2; ++p) {
        const int e = p * 2048 + tid * 8;
        const int r = e >> 6, c = e & 63;
        *(u16x8*)&Qs[r][c] = *(const u16x8*)(Qp + (bS + q0 + r) * Ddim + col0 + c);
    }

    float den_acc[4] = {0.f, 0.f, 0.f, 0.f};
    f32x4 xacc[4] = {};
    float local_sv = 0.f;
    const int svd = tid & 63;   // dk col for sumV
    const int svp = tid >> 6;   // k-chunk part

    for (int kt = 0; kt < 8; ++kt) {
        const int kbase = kt * 128;
        __syncthreads();   // previous iter done reading Ks/Vt (covers Q stage too)
#pragma unroll
        for (int p = 0; p < 4; ++p) {
            const int e = p * 2048 + tid * 8;
            const int r = e >> 6, c = e & 63;
            const u16x8 kv = *(const u16x8*)(Kp + (bS + kbase + r) * Ddim + col0 + c);
            *(u16x8*)&Ks[r][c] = kv;
            const u16x8 vv = *(const u16x8*)(Vp + (bS + kbase + r) * Ddim + col0 + c);
#pragma unroll
            for (int u = 0; u < 8; ++u) Vt[c + u][r] = vv[u];
        }
        if (tid < 128) pols[tid] = pol[bS + kbase + tid];
        __syncthreads();

        // scores S = Q . K^T   (16 q-rows x 128 kpos per wave)
        bf16x8 aq0 = *(const bf16x8*)&Qs[w * 16 + l15][quad * 8];
        bf16x8 aq1 = *(const bf16x8*)&Qs[w * 16 + l15][32 + quad * 8];
        f32x4 sc[8] = {};
#pragma unroll
        for (int nt = 0; nt < 8; ++nt) {
            bf16x8 b0 = *(const bf16x8*)&Ks[nt * 16 + l15][quad * 8];
            bf16x8 b1 = *(const bf16x8*)&Ks[nt * 16 + l15][32 + quad * 8];
            sc[nt] = __builtin_amdgcn_mfma_f32_16x16x32_bf16(aq0, b0, sc[nt], 0, 0, 0);
            sc[nt] = __builtin_amdgcn_mfma_f32_16x16x32_bf16(aq1, b1, sc[nt], 0, 0, 0);
        }
        // p = exp(s/8)*pol ; accumulate den ; write P (C-layout -> LDS)
#pragma unroll
        for (int nt = 0; nt < 8; ++nt) {
            const float pl = pols[nt * 16 + l15];
#pragma unroll
            for (int r = 0; r < 4; ++r) {
                const float p = __expf(sc[nt][r] * 0.125f) * pl;
                den_acc[r] += p;
                Pw[w][quad * 4 + r][nt * 16 + l15] = f2bf(p);
            }
        }
        __syncthreads();

        // X += P . V  (A-frags from Pw, B-frags from Vt)
        bf16x8 ap[4];
#pragma unroll
        for (int ks = 0; ks < 4; ++ks)
            ap[ks] = *(const bf16x8*)&Pw[w][l15][ks * 32 + quad * 8];
#pragma unroll
        for (int nt = 0; nt < 4; ++nt)
#pragma unroll
            for (int ks = 0; ks < 4; ++ks) {
                bf16x8 bv = *(const bf16x8*)&Vt[nt * 16 + l15][ks * 32 + quad * 8];
                xacc[nt] = __builtin_amdgcn_mfma_f32_16x16x32_bf16(ap[ks], bv,
                                                                   xacc[nt], 0, 0, 0);
            }
        // sumV partials (reads Vt; done before next barrier)
#pragma unroll
        for (int j = 0; j < 32; j += 8) {
            const u16x8 t = *(const u16x8*)&Vt[svd][svp * 32 + j];
#pragma unroll
            for (int u = 0; u < 8; ++u) local_sv += bf2f(t[u]);
        }
    }

    sumv_part[svp][svd] = local_sv;
    __syncthreads();
    if (tid < 64)
        sumv_s[tid] = sumv_part[0][tid] + sumv_part[1][tid] +
                      sumv_part[2][tid] + sumv_part[3][tid];
    __syncthreads();

    // reduce den across the 16 lanes of each quad
#pragma unroll
    for (int m = 1; m < 16; m <<= 1)
#pragma unroll
        for (int r = 0; r < 4; ++r)
            den_acc[r] += __shfl_xor(den_acc[r], m, 64);
    float inv[4];
#pragma unroll
    for (int r = 0; r < 4; ++r) inv[r] = 1.0f / (den_acc[r] + 1e-6f);

    const float EPSS = 1e-6f / 1024.0f;
#pragma unroll
    for (int nt = 0; nt < 4; ++nt)
#pragma unroll
        for (int r = 0; r < 4; ++r) {
            const int col = nt * 16 + l15;
            const float v = (xacc[nt][r] + EPSS * sumv_s[col]) * inv[r];
            const int rowq = q0 + w * 16 + quad * 4 + r;
            Xb[(bS + rowq) * Ddim + col0 + col] = f2bf(v);
        }
}

// ---------------------------------------------------------------------------
extern "C" void kernel_launch(void* const* d_in, const int* in_sizes, int n_in,
                              void* d_out, int out_size, void* d_ws, size_t ws_size,
                              hipStream_t stream) {
    const float* query   = (const float*)d_in[0];
    const float* key     = (const float*)d_in[1];
    const float* value   = (const float*)d_in[2];
    const float* policy  = (const float*)d_in[3];
    const float* wq_w    = (const float*)d_in[4];
    const float* wq_b    = (const float*)d_in[5];
    const float* wk_w    = (const float*)d_in[6];
    const float* wk_b    = (const float*)d_in[7];
    const float* wv_w    = (const float*)d_in[8];
    const float* wv_b    = (const float*)d_in[9];
    const float* dense_w = (const float*)d_in[10];
    const float* dense_b = (const float*)d_in[11];

    const size_t MM = 1u << 20;          // 1M elements
    const size_t A8 = 8 * MM;            // activation: 8M elements
    u16* qa  = (u16*)d_ws;
    u16* ka  = qa + A8;
    u16* va  = ka + A8;
    u16* wqb = va + A8;
    u16* wkb = wqb + MM;
    u16* wvb = wkb + MM;
    u16* wdb = wvb + MM;
    u16* Qp  = wdb + MM;
    u16* Kp  = Qp + A8;
    u16* Vp  = Kp + A8;
    u16* Xb  = Vp + A8;

    cvt_bf16<<<4096, 256, 0, stream>>>(query, qa, (int)A8);
    cvt_bf16<<<4096, 256, 0, stream>>>(key,   ka, (int)A8);
    cvt_bf16<<<4096, 256, 0, stream>>>(value, va, (int)A8);
    cvt_bf16<<<512, 256, 0, stream>>>(wq_w, wqb, (int)MM);
    cvt_bf16<<<512, 256, 0, stream>>>(wk_w, wkb, (int)MM);
    cvt_bf16<<<512, 256, 0, stream>>>(wv_w, wvb, (int)MM);
    cvt_bf16<<<512, 256, 0, stream>>>(dense_w, wdb, (int)MM);

    const dim3 gg(64, 8);   // 8192/128, 1024/128
    gemm_bt_mfma<true><<<gg, 256, 0, stream>>>(qa, wqb, wq_b, (void*)Qp);
    gemm_bt_mfma<true><<<gg, 256, 0, stream>>>(ka, wkb, wk_b, (void*)Kp);
    gemm_bt_mfma<true><<<gg, 256, 0, stream>>>(va, wvb, wv_b, (void*)Vp);

    const dim3 ga(128, 16);  // B*H, S/64
    attn_mfma<<<ga, 256, 0, stream>>>(Qp, Kp, Vp, policy, Xb);

    gemm_bt_mfma<false><<<gg, 256, 0, stream>>>(Xb, wdb, dense_b, d_out);
}

// Round 3
// 353.751 us; speedup vs baseline: 5.3483x; 1.1706x over previous
//
#include <hip/hip_runtime.h>

// MultiHeadedAttention B=8,S=1024,D=1024,H=16,dk=64 — bf16 MFMA pipeline.
// R3: conflict-free m97-style LDS layouts (inner dim = 32 u16, 64B rows),
// pre-transposed V, wave-private P (no 3rd barrier), fused QKV GEMM (z-grid),
// fused converts. p = exp(s/8)*pol; x = sum(p*v)/(sum p + EPS)  (EPS/S term
// dropped: contributes ~4e-11 abs, threshold is 1.6e-3).

#define Sdim 1024
#define Ddim 1024

typedef unsigned short u16;
typedef float f32x4 __attribute__((ext_vector_type(4)));
typedef __bf16 bf16x8 __attribute__((ext_vector_type(8)));
typedef u16 u16x8 __attribute__((ext_vector_type(8)));
typedef __attribute__((address_space(3))) void lds_void;
typedef __attribute__((address_space(1))) void gbl_void;

__device__ __forceinline__ u16 f2bf(float f) {
    unsigned u = __float_as_uint(f);
    u += 0x7fffu + ((u >> 16) & 1u);   // RNE
    return (u16)(u >> 16);
}
__device__ __forceinline__ void gld16(const void* g, void* l) {
    __builtin_amdgcn_global_load_lds((const gbl_void*)g, (lds_void*)l, 16, 0, 0);
}
#define MFMA16(a, b, c) __builtin_amdgcn_mfma_f32_16x16x32_bf16((a), (b), (c), 0, 0, 0)

// ---------------------------------------------------------------------------
// fused fp32->bf16 converts (grid.y selects tensor)
// ---------------------------------------------------------------------------
__global__ __launch_bounds__(256) void cvt3(const float* __restrict__ s0,
                                            const float* __restrict__ s1,
                                            const float* __restrict__ s2,
                                            u16* __restrict__ d0,
                                            u16* __restrict__ d1,
                                            u16* __restrict__ d2) {
    const int z = blockIdx.y;
    const float* s = z == 0 ? s0 : z == 1 ? s1 : s2;
    u16* d = z == 0 ? d0 : z == 1 ? d1 : d2;
    const int i = (blockIdx.x * 256 + threadIdx.x) * 8;
    const float4 a = *(const float4*)(s + i);
    const float4 b = *(const float4*)(s + i + 4);
    u16x8 o;
    o[0] = f2bf(a.x); o[1] = f2bf(a.y); o[2] = f2bf(a.z); o[3] = f2bf(a.w);
    o[4] = f2bf(b.x); o[5] = f2bf(b.y); o[6] = f2bf(b.z); o[7] = f2bf(b.w);
    *(u16x8*)(d + i) = o;
}
__global__ __launch_bounds__(256) void cvt4(const float* __restrict__ s0,
                                            const float* __restrict__ s1,
                                            const float* __restrict__ s2,
                                            const float* __restrict__ s3,
                                            u16* __restrict__ d0,
                                            u16* __restrict__ d1,
                                            u16* __restrict__ d2,
                                            u16* __restrict__ d3) {
    const int z = blockIdx.y;
    const float* s = z == 0 ? s0 : z == 1 ? s1 : z == 2 ? s2 : s3;
    u16* d = z == 0 ? d0 : z == 1 ? d1 : z == 2 ? d2 : d3;
    const int i = (blockIdx.x * 256 + threadIdx.x) * 8;
    const float4 a = *(const float4*)(s + i);
    const float4 b = *(const float4*)(s + i + 4);
    u16x8 o;
    o[0] = f2bf(a.x); o[1] = f2bf(a.y); o[2] = f2bf(a.z); o[3] = f2bf(a.w);
    o[4] = f2bf(b.x); o[5] = f2bf(b.y); o[6] = f2bf(b.z); o[7] = f2bf(b.w);
    *(u16x8*)(d + i) = o;
}

// ---------------------------------------------------------------------------
// GEMM body: C[M][1024] = A[M][1024] @ W[1024][1024]^T + bias  (m97 structure)
// ---------------------------------------------------------------------------
template <bool OUT_BF16>
__device__ __forceinline__ void gemm_body(const u16* __restrict__ A,
                                          const u16* __restrict__ W,
                                          const float* __restrict__ bias,
                                          void* __restrict__ Cout,
                                          u16* As, u16* Bs,
                                          int m0, int n0) {
    const int tid  = threadIdx.x;
    const int wave = tid >> 6;
    const int lane = tid & 63;
    const int l15  = lane & 15;
    const int quad = lane >> 4;
    const int wm = (wave >> 1) * 64;
    const int wn = (wave & 1) * 64;

    const int e0 = wave * 512 + lane * 8;
    const int r0 = e0 >> 5, c0 = e0 & 31;
    const int e1 = 2048 + e0;
    const int r1 = e1 >> 5, c1 = e1 & 31;
    const u16* Ag0 = A + (size_t)(m0 + r0) * Ddim + c0;
    const u16* Ag1 = A + (size_t)(m0 + r1) * Ddim + c1;
    const u16* Wg0 = W + (size_t)(n0 + r0) * Ddim + c0;
    const u16* Wg1 = W + (size_t)(n0 + r1) * Ddim + c1;
    u16* As0 = As + wave * 512;
    u16* As1 = As + 2048 + wave * 512;
    u16* Bs0 = Bs + wave * 512;
    u16* Bs1 = Bs + 2048 + wave * 512;

    f32x4 acc[4][4] = {};

    for (int k0 = 0; k0 < Ddim; k0 += 32) {
        __syncthreads();
        gld16(Ag0 + k0, As0);
        gld16(Ag1 + k0, As1);
        gld16(Wg0 + k0, Bs0);
        gld16(Wg1 + k0, Bs1);
        __syncthreads();
        bf16x8 af[4], bfr[4];
#pragma unroll
        for (int i = 0; i < 4; ++i)
            af[i] = *(const bf16x8*)(As + (wm + i * 16 + l15) * 32 + quad * 8);
#pragma unroll
        for (int j = 0; j < 4; ++j)
            bfr[j] = *(const bf16x8*)(Bs + (wn + j * 16 + l15) * 32 + quad * 8);
#pragma unroll
        for (int i = 0; i < 4; ++i)
#pragma unroll
            for (int j = 0; j < 4; ++j)
                acc[i][j] = MFMA16(af[i], bfr[j], acc[i][j]);
    }

    float bv[4];
#pragma unroll
    for (int j = 0; j < 4; ++j) bv[j] = bias[n0 + wn + j * 16 + l15];
#pragma unroll
    for (int i = 0; i < 4; ++i)
#pragma unroll
        for (int j = 0; j < 4; ++j)
#pragma unroll
            for (int r = 0; r < 4; ++r) {
                const int row = m0 + wm + i * 16 + quad * 4 + r;
                const int col = n0 + wn + j * 16 + l15;
                const float v = acc[i][j][r] + bv[j];
                if (OUT_BF16)
                    ((u16*)Cout)[(size_t)row * Ddim + col] = f2bf(v);
                else
                    ((float*)Cout)[(size_t)row * Ddim + col] = v;
            }
}

// fused QKV projection: blockIdx.z selects (A, W, bias, C)
__global__ __launch_bounds__(256) void gemm_qkv(const u16* __restrict__ A0, const u16* __restrict__ A1,
                                                const u16* __restrict__ A2,
                                                const u16* __restrict__ W0, const u16* __restrict__ W1,
                                                const u16* __restrict__ W2,
                                                const float* __restrict__ b0, const float* __restrict__ b1,
                                                const float* __restrict__ b2,
                                                u16* __restrict__ C0, u16* __restrict__ C1,
                                                u16* __restrict__ C2) {
    __shared__ __align__(16) u16 As[128 * 32];
    __shared__ __align__(16) u16 Bs[128 * 32];
    const int z = blockIdx.z;
    const u16* A = z == 0 ? A0 : z == 1 ? A1 : A2;
    const u16* W = z == 0 ? W0 : z == 1 ? W1 : W2;
    const float* bias = z == 0 ? b0 : z == 1 ? b1 : b2;
    u16* C = z == 0 ? C0 : z == 1 ? C1 : C2;
    gemm_body<true>(A, W, bias, (void*)C, As, Bs, blockIdx.x * 128, blockIdx.y * 128);
}

__global__ __launch_bounds__(256) void gemm_dense(const u16* __restrict__ A,
                                                  const u16* __restrict__ W,
                                                  const float* __restrict__ bias,
                                                  float* __restrict__ C) {
    __shared__ __align__(16) u16 As[128 * 32];
    __shared__ __align__(16) u16 Bs[128 * 32];
    gemm_body<false>(A, W, bias, (void*)C, As, Bs, blockIdx.x * 128, blockIdx.y * 128);
}

// ---------------------------------------------------------------------------
// V transpose: Vp[B*S][D] (bf16) -> Vt_g[(b*16+h)*64 + d][S]
// ---------------------------------------------------------------------------
__global__ __launch_bounds__(256) void transp_v(const u16* __restrict__ Vp,
                                                u16* __restrict__ Vt) {
    __shared__ __align__(16) u16 Ts[64][72];
    const int bh = blockIdx.x, s0 = blockIdx.y * 64;
    const int b = bh >> 4, h = bh & 15;
    const int tid = threadIdx.x;
#pragma unroll
    for (int p = 0; p < 2; ++p) {
        const int e = p * 2048 + tid * 8;
        const int r = e >> 6, c = e & 63;
        *(u16x8*)&Ts[r][c] =
            *(const u16x8*)(Vp + ((size_t)(b * Sdim + s0 + r)) * Ddim + h * 64 + c);
    }
    __syncthreads();
    const int d = tid >> 2, sp = tid & 3;
#pragma unroll
    for (int g = 0; g < 2; ++g) {
        u16x8 o;
#pragma unroll
        for (int j = 0; j < 8; ++j) o[j] = Ts[sp * 16 + g * 8 + j][d];
        *(u16x8*)(Vt + ((size_t)(bh * 64 + d)) * Sdim + s0 + sp * 16 + g * 8) = o;
    }
}

// ---------------------------------------------------------------------------
// MFMA flash attention with policy normalization.
// Block = (64 q-rows, bh). 4 waves as 2x2: wm = q-half (32 rows), wn = kpos-half (64).
// All tiles are [row][32] u16 (64B rows) -> conflict-free m97 fragment reads.
// ---------------------------------------------------------------------------
__global__ __launch_bounds__(256) void attn_mfma(const u16* __restrict__ Qp,
                                                 const u16* __restrict__ Kp,
                                                 const u16* __restrict__ Vt,
                                                 const float* __restrict__ pol,
                                                 u16* __restrict__ Xb) {
    __shared__ __align__(16) u16 lds[29184];           // 58368 B
    u16* Qs = lds;                       // [2ks][64][32]   4096 u16
    u16* Ks = lds + 4096;                // [2ks][128][32]  8192
    u16* Vs = lds + 12288;               // [4ck][64][32]   8192
    u16* Pg = lds + 20480;               // [w][2i][2ks][16][32] 8192
    float* Xred = (float*)(lds + 4096);  // [64][68] f32 (aliases Ks+Vs, post-loop)
    u16* XbR = lds + 20480;              // [64][64] (aliases Pg, post-loop)
    float* denb = (float*)(lds + 28672); // [2][64]
    float* pols = (float*)(lds + 28928); // [128]

    const int tid  = threadIdx.x;
    const int wave = tid >> 6;
    const int lane = tid & 63;
    const int l15  = lane & 15;
    const int quad = lane >> 4;
    const int wm = wave >> 1;     // q-half
    const int wn = wave & 1;      // kpos-half
    const int q0 = blockIdx.x * 64;
    const int bh = blockIdx.y;
    const int b = bh >> 4;
    const size_t bS = (size_t)b * Sdim;
    const int col0 = (bh & 15) * 64;
    const int lr4 = lane >> 2;          // 0..15 (row within 16-row staging chunk)
    const int lc8 = (lane & 3) * 8;     // 0,8,16,24

    // stage Q once (each wave: 16 rows x both ks-halves)
#pragma unroll
    for (int ks = 0; ks < 2; ++ks)
        gld16(Qp + (bS + q0 + wave * 16 + lr4) * Ddim + col0 + ks * 32 + lc8,
              Qs + (ks * 64 + wave * 16) * 32);

    f32x4 xacc[2][4] = {};
    float den[2][4] = {};

    for (int kt = 0; kt < 8; ++kt) {
        const int kbase = kt * 128;
        __syncthreads();
        // stage K[128][64]: 16 insts, 4 per wave
#pragma unroll
        for (int ks = 0; ks < 2; ++ks)
#pragma unroll
            for (int tt = 0; tt < 2; ++tt) {
                const int rblk = wave * 2 + tt;
                gld16(Kp + (bS + kbase + rblk * 16 + lr4) * Ddim + col0 + ks * 32 + lc8,
                      Ks + (ks * 128 + rblk * 16) * 32);
            }
        // stage V^T[64 d][128 kpos]: ck = wave's 32-kpos chunk
#pragma unroll
        for (int tt = 0; tt < 4; ++tt)
            gld16(Vt + ((size_t)(bh * 64 + tt * 16 + lr4)) * Sdim + kbase + wave * 32 + lc8,
                  Vs + (wave * 64 + tt * 16) * 32);
        if (tid < 128) pols[tid] = pol[bS + kbase + tid];
        __syncthreads();

        // S = Q.K^T : wave computes [32 q][64 kpos]
        bf16x8 aq[2][2];
#pragma unroll
        for (int i = 0; i < 2; ++i)
#pragma unroll
            for (int ks = 0; ks < 2; ++ks)
                aq[i][ks] = *(const bf16x8*)(Qs + (ks * 64 + wm * 32 + i * 16 + l15) * 32 + quad * 8);
#pragma unroll
        for (int i = 0; i < 2; ++i)
#pragma unroll
            for (int nt = 0; nt < 4; ++nt) {
                f32x4 sc = {};
#pragma unroll
                for (int ks = 0; ks < 2; ++ks) {
                    const bf16x8 bk =
                        *(const bf16x8*)(Ks + (ks * 128 + wn * 64 + nt * 16 + l15) * 32 + quad * 8);
                    sc = MFMA16(aq[i][ks], bk, sc);
                }
                const float pl = pols[wn * 64 + nt * 16 + l15];
#pragma unroll
                for (int r = 0; r < 4; ++r) {
                    const float p = __expf(sc[r] * 0.125f) * pl;
                    den[i][r] += p;
                    // C-layout (m=quad*4+r, k=nt*16+l15) -> A-layout slot
                    Pg[(((wave * 2 + i) * 2 + (nt >> 1)) * 16 + quad * 4 + r) * 32 +
                       (nt & 1) * 16 + l15] = f2bf(p);
                }
            }
        // X += P.V (wave-private P; compiler inserts lgkmcnt before reads)
#pragma unroll
        for (int i = 0; i < 2; ++i) {
            bf16x8 ap[2];
#pragma unroll
            for (int ks = 0; ks < 2; ++ks)
                ap[ks] = *(const bf16x8*)(Pg + (((wave * 2 + i) * 2 + ks) * 16 + l15) * 32 + quad * 8);
#pragma unroll
            for (int nd = 0; nd < 4; ++nd)
#pragma unroll
                for (int ks = 0; ks < 2; ++ks) {
                    const bf16x8 bv =
                        *(const bf16x8*)(Vs + ((wn * 2 + ks) * 64 + nd * 16 + l15) * 32 + quad * 8);
                    xacc[i][nd] = MFMA16(ap[ks], bv, xacc[i][nd]);
                }
        }
    }

    __syncthreads();   // all waves done with Ks/Vs/Pg -> safe to alias

    // reduce den over the 16 l15 lanes (cols), then publish per wn-half
#pragma unroll
    for (int m = 1; m < 16; m <<= 1)
#pragma unroll
        for (int i = 0; i < 2; ++i)
#pragma unroll
            for (int r = 0; r < 4; ++r)
                den[i][r] += __shfl_xor(den[i][r], m, 64);
    if (l15 == 0)
#pragma unroll
        for (int i = 0; i < 2; ++i)
#pragma unroll
            for (int r = 0; r < 4; ++r)
                denb[wn * 64 + wm * 32 + i * 16 + quad * 4 + r] = den[i][r];
    // wn==1 waves publish X partials
    if (wn == 1)
#pragma unroll
        for (int i = 0; i < 2; ++i)
#pragma unroll
            for (int nd = 0; nd < 4; ++nd)
#pragma unroll
                for (int r = 0; r < 4; ++r)
                    Xred[(wm * 32 + i * 16 + quad * 4 + r) * 68 + nd * 16 + l15] = xacc[i][nd][r];
    __syncthreads();

    if (wn == 0) {
#pragma unroll
        for (int i = 0; i < 2; ++i) {
            float inv[4];
#pragma unroll
            for (int r = 0; r < 4; ++r) {
                const int row = wm * 32 + i * 16 + quad * 4 + r;
                inv[r] = 1.0f / (denb[row] + denb[64 + row] + 1e-6f);
            }
#pragma unroll
            for (int nd = 0; nd < 4; ++nd)
#pragma unroll
                for (int r = 0; r < 4; ++r) {
                    const int row = wm * 32 + i * 16 + quad * 4 + r;
                    const float x = xacc[i][nd][r] + Xred[row * 68 + nd * 16 + l15];
                    XbR[row * 64 + nd * 16 + l15] = f2bf(x * inv[r]);
                }
        }
    }
    __syncthreads();

    // coalesced store of the 64x64 output tile
#pragma unroll
    for (int g = 0; g < 2; ++g) {
        const int e = g * 2048 + tid * 8;
        const int rr = e >> 6, cc = e & 63;
        const u16x8 o = *(const u16x8*)(XbR + rr * 64 + cc);
        *(u16x8*)(Xb + (bS + q0 + rr) * Ddim + col0 + cc) = o;
    }
}

// ---------------------------------------------------------------------------
extern "C" void kernel_launch(void* const* d_in, const int* in_sizes, int n_in,
                              void* d_out, int out_size, void* d_ws, size_t ws_size,
                              hipStream_t stream) {
    const float* query   = (const float*)d_in[0];
    const float* key     = (const float*)d_in[1];
    const float* value   = (const float*)d_in[2];
    const float* policy  = (const float*)d_in[3];
    const float* wq_w    = (const float*)d_in[4];
    const float* wq_b    = (const float*)d_in[5];
    const float* wk_w    = (const float*)d_in[6];
    const float* wk_b    = (const float*)d_in[7];
    const float* wv_w    = (const float*)d_in[8];
    const float* wv_b    = (const float*)d_in[9];
    const float* dense_w = (const float*)d_in[10];
    const float* dense_b = (const float*)d_in[11];

    const size_t MM = 1u << 20;
    const size_t A8 = 8 * MM;
    u16* qa  = (u16*)d_ws;        // later aliased as Xb
    u16* ka  = qa + A8;           // later aliased as Vtg
    u16* va  = ka + A8;
    u16* wqb = va + A8;
    u16* wkb = wqb + MM;
    u16* wvb = wkb + MM;
    u16* wdb = wvb + MM;
    u16* Qp  = wdb + MM;
    u16* Kp  = Qp + A8;
    u16* Vp  = Kp + A8;
    u16* Vtg = ka;                // safe: ka consumed by gemm_qkv before transp_v
    u16* Xb  = qa;                // safe: qa consumed by gemm_qkv before attn

    cvt3<<<dim3(4096, 3), 256, 0, stream>>>(query, key, value, qa, ka, va);
    cvt4<<<dim3(512, 4), 256, 0, stream>>>(wq_w, wk_w, wv_w, dense_w, wqb, wkb, wvb, wdb);

    gemm_qkv<<<dim3(64, 8, 3), 256, 0, stream>>>(qa, ka, va, wqb, wkb, wvb,
                                                 wq_b, wk_b, wv_b, Qp, Kp, Vp);
    transp_v<<<dim3(128, 16), 256, 0, stream>>>(Vp, Vtg);

    attn_mfma<<<dim3(16, 128), 256, 0, stream>>>(Qp, Kp, Vtg, policy, Xb);

    gemm_dense<<<dim3(64, 8), 256, 0, stream>>>(Xb, wdb, dense_b, (float*)d_out);
}

// Round 4
// 309.190 us; speedup vs baseline: 6.1191x; 1.1441x over previous
//
#include <hip/hip_runtime.h>

// MultiHeadedAttention B=8,S=1024,D=1024,H=16,dk=64 — bf16 MFMA pipeline.
// R4: attention rewritten on 32x32x16 MFMA. S^T = K.Q^T puts q in lane dim;
// P converted C-layout -> A-layout IN REGISTERS via __shfl_xor(32)+cndmask
// (no P LDS round trip). Wave owns 64 q-rows, Q frags cached in VGPRs.
// Scale 1/8 folded into wq at convert time. p = exp(s')*pol;
// x = sum(p*v)/(sum p + EPS).

#define Sdim 1024
#define Ddim 1024

typedef unsigned short u16;
typedef float f32x4 __attribute__((ext_vector_type(4)));
typedef float f32x16 __attribute__((ext_vector_type(16)));
typedef __bf16 bf16x8 __attribute__((ext_vector_type(8)));
typedef u16 u16x8 __attribute__((ext_vector_type(8)));
typedef __attribute__((address_space(3))) void lds_void;
typedef __attribute__((address_space(1))) void gbl_void;

__device__ __forceinline__ u16 f2bf(float f) {
    unsigned u = __float_as_uint(f);
    u += 0x7fffu + ((u >> 16) & 1u);   // RNE
    return (u16)(u >> 16);
}
__device__ __forceinline__ void gld16(const void* g, void* l) {
    __builtin_amdgcn_global_load_lds((const gbl_void*)g, (lds_void*)l, 16, 0, 0);
}
// pack two f32 -> two bf16 (round-half-up) in one u32 via v_perm
__device__ __forceinline__ unsigned pk_bf16(float lo, float hi) {
    const unsigned ul = __float_as_uint(lo) + 0x8000u;
    const unsigned uh = __float_as_uint(hi) + 0x8000u;
    return __builtin_amdgcn_perm(uh, ul, 0x07060302u);
}
#define MFMA16(a, b, c) __builtin_amdgcn_mfma_f32_16x16x32_bf16((a), (b), (c), 0, 0, 0)
#define MFMA32(a, b, c) __builtin_amdgcn_mfma_f32_32x32x16_bf16((a), (b), (c), 0, 0, 0)

// ---------------------------------------------------------------------------
// fused fp32->bf16 converts; y=0..2 activations (8M), y=3..6 weights (1M).
// y==3 (wq) is scaled by 0.125 (folds the 1/sqrt(dk) into Q projection).
// ---------------------------------------------------------------------------
__global__ __launch_bounds__(256) void cvt_all(const float* __restrict__ s0,
                                               const float* __restrict__ s1,
                                               const float* __restrict__ s2,
                                               const float* __restrict__ s3,
                                               const float* __restrict__ s4,
                                               const float* __restrict__ s5,
                                               const float* __restrict__ s6,
                                               u16* __restrict__ d0, u16* __restrict__ d1,
                                               u16* __restrict__ d2, u16* __restrict__ d3,
                                               u16* __restrict__ d4, u16* __restrict__ d5,
                                               u16* __restrict__ d6) {
    const int z = blockIdx.y;
    if (z >= 3 && blockIdx.x >= 512) return;
    const float* s = z == 0 ? s0 : z == 1 ? s1 : z == 2 ? s2 : z == 3 ? s3
                   : z == 4 ? s4 : z == 5 ? s5 : s6;
    u16* d = z == 0 ? d0 : z == 1 ? d1 : z == 2 ? d2 : z == 3 ? d3
           : z == 4 ? d4 : z == 5 ? d5 : d6;
    const float sc = (z == 3) ? 0.125f : 1.0f;
    const int i = (blockIdx.x * 256 + threadIdx.x) * 8;
    const float4 a = *(const float4*)(s + i);
    const float4 b = *(const float4*)(s + i + 4);
    u16x8 o;
    o[0] = f2bf(a.x * sc); o[1] = f2bf(a.y * sc); o[2] = f2bf(a.z * sc); o[3] = f2bf(a.w * sc);
    o[4] = f2bf(b.x * sc); o[5] = f2bf(b.y * sc); o[6] = f2bf(b.z * sc); o[7] = f2bf(b.w * sc);
    *(u16x8*)(d + i) = o;
}

// ---------------------------------------------------------------------------
// GEMM body: C[M][1024] = A[M][1024] @ W[1024][1024]^T + bias*bscale
// (m97 structure, 128x128 tile, BK=32, 16x16x32 MFMA)
// ---------------------------------------------------------------------------
template <bool OUT_BF16>
__device__ __forceinline__ void gemm_body(const u16* __restrict__ A,
                                          const u16* __restrict__ W,
                                          const float* __restrict__ bias, float bscale,
                                          void* __restrict__ Cout,
                                          u16* As, u16* Bs,
                                          int m0, int n0) {
    const int tid  = threadIdx.x;
    const int wave = tid >> 6;
    const int lane = tid & 63;
    const int l15  = lane & 15;
    const int quad = lane >> 4;
    const int wm = (wave >> 1) * 64;
    const int wn = (wave & 1) * 64;

    const int e0 = wave * 512 + lane * 8;
    const int r0 = e0 >> 5, c0 = e0 & 31;
    const int e1 = 2048 + e0;
    const int r1 = e1 >> 5, c1 = e1 & 31;
    const u16* Ag0 = A + (size_t)(m0 + r0) * Ddim + c0;
    const u16* Ag1 = A + (size_t)(m0 + r1) * Ddim + c1;
    const u16* Wg0 = W + (size_t)(n0 + r0) * Ddim + c0;
    const u16* Wg1 = W + (size_t)(n0 + r1) * Ddim + c1;
    u16* As0 = As + wave * 512;
    u16* As1 = As + 2048 + wave * 512;
    u16* Bs0 = Bs + wave * 512;
    u16* Bs1 = Bs + 2048 + wave * 512;

    f32x4 acc[4][4] = {};

    for (int k0 = 0; k0 < Ddim; k0 += 32) {
        __syncthreads();
        gld16(Ag0 + k0, As0);
        gld16(Ag1 + k0, As1);
        gld16(Wg0 + k0, Bs0);
        gld16(Wg1 + k0, Bs1);
        __syncthreads();
        bf16x8 af[4], bfr[4];
#pragma unroll
        for (int i = 0; i < 4; ++i)
            af[i] = *(const bf16x8*)(As + (wm + i * 16 + l15) * 32 + quad * 8);
#pragma unroll
        for (int j = 0; j < 4; ++j)
            bfr[j] = *(const bf16x8*)(Bs + (wn + j * 16 + l15) * 32 + quad * 8);
#pragma unroll
        for (int i = 0; i < 4; ++i)
#pragma unroll
            for (int j = 0; j < 4; ++j)
                acc[i][j] = MFMA16(af[i], bfr[j], acc[i][j]);
    }

    float bv[4];
#pragma unroll
    for (int j = 0; j < 4; ++j) bv[j] = bias[n0 + wn + j * 16 + l15] * bscale;
#pragma unroll
    for (int i = 0; i < 4; ++i)
#pragma unroll
        for (int j = 0; j < 4; ++j)
#pragma unroll
            for (int r = 0; r < 4; ++r) {
                const int row = m0 + wm + i * 16 + quad * 4 + r;
                const int col = n0 + wn + j * 16 + l15;
                const float v = acc[i][j][r] + bv[j];
                if (OUT_BF16)
                    ((u16*)Cout)[(size_t)row * Ddim + col] = f2bf(v);
                else
                    ((float*)Cout)[(size_t)row * Ddim + col] = v;
            }
}

__global__ __launch_bounds__(256) void gemm_qkv(const u16* __restrict__ A0, const u16* __restrict__ A1,
                                                const u16* __restrict__ A2,
                                                const u16* __restrict__ W0, const u16* __restrict__ W1,
                                                const u16* __restrict__ W2,
                                                const float* __restrict__ b0, const float* __restrict__ b1,
                                                const float* __restrict__ b2,
                                                u16* __restrict__ C0, u16* __restrict__ C1,
                                                u16* __restrict__ C2) {
    __shared__ __align__(16) u16 As[128 * 32];
    __shared__ __align__(16) u16 Bs[128 * 32];
    const int z = blockIdx.z;
    const u16* A = z == 0 ? A0 : z == 1 ? A1 : A2;
    const u16* W = z == 0 ? W0 : z == 1 ? W1 : W2;
    const float* bias = z == 0 ? b0 : z == 1 ? b1 : b2;
    u16* C = z == 0 ? C0 : z == 1 ? C1 : C2;
    const float bsc = (z == 0) ? 0.125f : 1.0f;   // wq path is pre-scaled
    gemm_body<true>(A, W, bias, bsc, (void*)C, As, Bs, blockIdx.x * 128, blockIdx.y * 128);
}

__global__ __launch_bounds__(256) void gemm_dense(const u16* __restrict__ A,
                                                  const u16* __restrict__ W,
                                                  const float* __restrict__ bias,
                                                  float* __restrict__ C) {
    __shared__ __align__(16) u16 As[128 * 32];
    __shared__ __align__(16) u16 Bs[128 * 32];
    gemm_body<false>(A, W, bias, 1.0f, (void*)C, As, Bs, blockIdx.x * 128, blockIdx.y * 128);
}

// ---------------------------------------------------------------------------
// V transpose: Vp[B*S][D] (bf16) -> Vt_g[(b*16+h)*64 + d][S]
// ---------------------------------------------------------------------------
__global__ __launch_bounds__(256) void transp_v(const u16* __restrict__ Vp,
                                                u16* __restrict__ Vt) {
    __shared__ __align__(16) u16 Ts[64][72];
    const int bh = blockIdx.x, s0 = blockIdx.y * 64;
    const int b = bh >> 4, h = bh & 15;
    const int tid = threadIdx.x;
#pragma unroll
    for (int p = 0; p < 2; ++p) {
        const int e = p * 2048 + tid * 8;
        const int r = e >> 6, c = e & 63;
        *(u16x8*)&Ts[r][c] =
            *(const u16x8*)(Vp + ((size_t)(b * Sdim + s0 + r)) * Ddim + h * 64 + c);
    }
    __syncthreads();
    const int d = tid >> 2, sp = tid & 3;
#pragma unroll
    for (int g = 0; g < 2; ++g) {
        u16x8 o;
#pragma unroll
        for (int j = 0; j < 8; ++j) o[j] = Ts[sp * 16 + g * 8 + j][d];
        *(u16x8*)(Vt + ((size_t)(bh * 64 + d)) * Sdim + s0 + sp * 16 + g * 8) = o;
    }
}

// ---------------------------------------------------------------------------
// Attention on 32x32x16 MFMA. Block = 256 q-rows of one (b,h); wave owns 64 q.
// Per 64-kpos tile: S^T = K.Q^T (A=K-frag, B=Q-frag cached in regs);
// p = exp(s)*pol in f32; P regs re-laid C->A via shfl_xor(32)+cndmask;
// X += P.V^T. All LDS tiles stride 72 u16 (conflict-free for 32-row frags).
// ---------------------------------------------------------------------------
__global__ __launch_bounds__(256, 2) void attn_mfma(const u16* __restrict__ Qp,
                                                    const u16* __restrict__ Kp,
                                                    const u16* __restrict__ Vt,
                                                    const float* __restrict__ pol,
                                                    u16* __restrict__ Xb) {
    __shared__ __align__(16) u16 lds[28288];    // 56576 B
    u16* Qs = lds;                              // 256 x 72  (later: Xout)
    u16* Ks = lds + 18432;                      // 64 x 72   K[kpos][dk]
    u16* Vs = lds + 23040;                      // 64 x 72   V^T[d][kpos]
    float* pols = (float*)(lds + 27648);        // [64]
    float* denb = pols + 64;                    // [256] inv-den

    const int tid  = threadIdx.x;
    const int w    = tid >> 6;
    const int lane = tid & 63;
    const int l31  = lane & 31;
    const unsigned hsel = lane >> 5;            // half selector
    const int q0 = blockIdx.x * 256;
    const int bh = blockIdx.y;
    const size_t bS = (size_t)(bh >> 4) * Sdim;
    const int col0 = (bh & 15) * 64;
    const int sr = tid >> 2;                    // staging row 0..63
    const int sc4 = tid & 3;                    // staging chunk base

    // ---- stage Q tile 256x64 and load Q B-frags into registers ----
#pragma unroll
    for (int rg = 0; rg < 4; ++rg) {
        const int r = rg * 64 + sr;
#pragma unroll
        for (int g = 0; g < 2; ++g) {
            const int ch = sc4 + g * 4;
            *(u16x8*)(Qs + r * 72 + ch * 8) =
                *(const u16x8*)(Qp + (bS + q0 + r) * Ddim + col0 + ch * 8);
        }
    }
    __syncthreads();
    bf16x8 Qf[2][4];
#pragma unroll
    for (int qt = 0; qt < 2; ++qt)
#pragma unroll
        for (int dkt = 0; dkt < 4; ++dkt)
            Qf[qt][dkt] = *(const bf16x8*)(Qs + (w * 64 + qt * 32 + l31) * 72 +
                                           dkt * 16 + hsel * 8);

    f32x16 X[2][2] = {};
    float den[2] = {0.f, 0.f};

    for (int kt = 0; kt < 16; ++kt) {
        const int kbase = kt * 64;
        __syncthreads();
        // stage K[64][64] and V^T[64][64]
#pragma unroll
        for (int g = 0; g < 2; ++g) {
            const int ch = sc4 + g * 4;
            *(u16x8*)(Ks + sr * 72 + ch * 8) =
                *(const u16x8*)(Kp + (bS + kbase + sr) * Ddim + col0 + ch * 8);
            *(u16x8*)(Vs + sr * 72 + ch * 8) =
                *(const u16x8*)(Vt + ((size_t)(bh * 64 + sr)) * Sdim + kbase + ch * 8);
        }
        if (tid < 64) pols[tid] = pol[bS + kbase + tid];
        __syncthreads();

#pragma unroll
        for (int t32 = 0; t32 < 2; ++t32) {
            // pol per C-layout row (broadcast reads; uniform per (e,half))
            float polv[16];
#pragma unroll
            for (int e = 0; e < 16; ++e)
                polv[e] = pols[t32 * 32 + (e & 3) + 8 * (e >> 2) + 4 * hsel];
            bf16x8 Kf[4];
#pragma unroll
            for (int dkt = 0; dkt < 4; ++dkt)
                Kf[dkt] = *(const bf16x8*)(Ks + (t32 * 32 + l31) * 72 +
                                           dkt * 16 + hsel * 8);
#pragma unroll
            for (int qt = 0; qt < 2; ++qt) {
                f32x16 S = {};
#pragma unroll
                for (int dkt = 0; dkt < 4; ++dkt)
                    S = MFMA32(Kf[dkt], Qf[qt][dkt], S);   // D[kpos][q]
                // softmax numerator (f32), accumulate den per-lane (q = l31)
                float p[16];
#pragma unroll
                for (int e = 0; e < 16; ++e) {
                    p[e] = __expf(S[e]) * polv[e];
                    den[qt] += p[e];
                }
                // pack pairs along kpos rows: pk_[2g]=(c0,c1), pk_[2g+1]=(c2,c3)
                unsigned pk_[8], sw[8];
#pragma unroll
                for (int g = 0; g < 4; ++g) {
                    pk_[2 * g]     = pk_bf16(p[4 * g + 0], p[4 * g + 1]);
                    pk_[2 * g + 1] = pk_bf16(p[4 * g + 2], p[4 * g + 3]);
                }
#pragma unroll
                for (int i = 0; i < 8; ++i)
                    sw[i] = (unsigned)__shfl_xor((int)pk_[i], 32);
                // P A-frags for the two 16-k tiles of this 32-kpos block
#pragma unroll
                for (int tau = 0; tau < 2; ++tau) {
                    union { unsigned u[4]; bf16x8 v; } Af;
                    Af.u[0] = hsel ? sw[(2 * tau + 1) * 2 + 0] : pk_[(2 * tau) * 2 + 0];
                    Af.u[1] = hsel ? sw[(2 * tau + 1) * 2 + 1] : pk_[(2 * tau) * 2 + 1];
                    Af.u[2] = hsel ? pk_[(2 * tau + 1) * 2 + 0] : sw[(2 * tau) * 2 + 0];
                    Af.u[3] = hsel ? pk_[(2 * tau + 1) * 2 + 1] : sw[(2 * tau) * 2 + 1];
#pragma unroll
                    for (int ndt = 0; ndt < 2; ++ndt) {
                        const bf16x8 Vf =
                            *(const bf16x8*)(Vs + (ndt * 32 + l31) * 72 +
                                             t32 * 32 + tau * 16 + hsel * 8);
                        X[qt][ndt] = MFMA32(Af.v, Vf, X[qt][ndt]);  // D[q][d]
                    }
                }
            }
        }
    }

    // ---- epilogue: den reduce, normalize, stage to LDS, coalesced store ----
#pragma unroll
    for (int qt = 0; qt < 2; ++qt) {
        den[qt] += __shfl_xor(den[qt], 32);
        denb[w * 64 + qt * 32 + l31] = 1.0f / (den[qt] + 1e-6f);
    }
    u16* Xout = Qs;   // Q frags live in regs; Qs region reused (barriers below)
#pragma unroll
    for (int qt = 0; qt < 2; ++qt) {
        float invv[16];
#pragma unroll
        for (int e = 0; e < 16; ++e)
            invv[e] = denb[w * 64 + qt * 32 + (e & 3) + 8 * (e >> 2) + 4 * hsel];
#pragma unroll
        for (int ndt = 0; ndt < 2; ++ndt)
#pragma unroll
            for (int e = 0; e < 16; ++e) {
                const int rho = (e & 3) + 8 * (e >> 2) + 4 * hsel;
                Xout[(w * 64 + qt * 32 + rho) * 72 + ndt * 32 + l31] =
                    f2bf(X[qt][ndt][e] * invv[e]);
            }
    }
    __syncthreads();
#pragma unroll
    for (int rg = 0; rg < 4; ++rg) {
        const int r = rg * 64 + sr;
#pragma unroll
        for (int g = 0; g < 2; ++g) {
            const int ch = sc4 + g * 4;
            *(u16x8*)(Xb + (bS + q0 + r) * Ddim + col0 + ch * 8) =
                *(const u16x8*)(Xout + r * 72 + ch * 8);
        }
    }
}

// ---------------------------------------------------------------------------
extern "C" void kernel_launch(void* const* d_in, const int* in_sizes, int n_in,
                              void* d_out, int out_size, void* d_ws, size_t ws_size,
                              hipStream_t stream) {
    const float* query   = (const float*)d_in[0];
    const float* key     = (const float*)d_in[1];
    const float* value   = (const float*)d_in[2];
    const float* policy  = (const float*)d_in[3];
    const float* wq_w    = (const float*)d_in[4];
    const float* wq_b    = (const float*)d_in[5];
    const float* wk_w    = (const float*)d_in[6];
    const float* wk_b    = (const float*)d_in[7];
    const float* wv_w    = (const float*)d_in[8];
    const float* wv_b    = (const float*)d_in[9];
    const float* dense_w = (const float*)d_in[10];
    const float* dense_b = (const float*)d_in[11];

    const size_t MM = 1u << 20;
    const size_t A8 = 8 * MM;
    u16* qa  = (u16*)d_ws;        // later aliased as Xb
    u16* ka  = qa + A8;           // later aliased as Vtg
    u16* va  = ka + A8;
    u16* wqb = va + A8;
    u16* wkb = wqb + MM;
    u16* wvb = wkb + MM;
    u16* wdb = wvb + MM;
    u16* Qp  = wdb + MM;
    u16* Kp  = Qp + A8;
    u16* Vp  = Kp + A8;
    u16* Vtg = ka;                // safe: ka consumed by gemm_qkv before transp_v
    u16* Xb  = qa;                // safe: qa consumed by gemm_qkv before attn

    cvt_all<<<dim3(4096, 7), 256, 0, stream>>>(query, key, value, wq_w, wk_w, wv_w, dense_w,
                                               qa, ka, va, wqb, wkb, wvb, wdb);

    gemm_qkv<<<dim3(64, 8, 3), 256, 0, stream>>>(qa, ka, va, wqb, wkb, wvb,
                                                 wq_b, wk_b, wv_b, Qp, Kp, Vp);
    transp_v<<<dim3(128, 16), 256, 0, stream>>>(Vp, Vtg);

    attn_mfma<<<dim3(4, 128), 256, 0, stream>>>(Qp, Kp, Vtg, policy, Xb);

    gemm_dense<<<dim3(64, 8), 256, 0, stream>>>(Xb, wdb, dense_b, (float*)d_out);
}